// Round 1
// baseline (2785.843 us; speedup 1.0000x reference)
//
#include <hip/hip_runtime.h>
#include <math.h>

// Problem constants
#define NN    8
#define CC_   96
#define HH    56
#define WW    56
#define HWHW  (HH*WW)            // 3136
#define NPIX  (NN*HWHW)          // 25088
#define NELEM (NN*CC_*HWHW)      // 2408448
#define GROUPS 4
#define IG    24                 // channels per group
#define KTAP  216                // 24*9
#define NITER 25
#define EPSV  1e-12f

// ---------------------------------------------------------------------------
// Weight normalization: w = |w| / (sum_{i,kh,kw} |w| + EPS), per output channel
__global__ void wnorm_kernel(const float* __restrict__ w_in, float* __restrict__ w_out) {
    int o = blockIdx.x;          // 96
    int t = threadIdx.x;         // 256
    float myv = 0.f;
    if (t < KTAP) myv = fabsf(w_in[o*KTAP + t]);
    float v = myv;
    #pragma unroll
    for (int off = 32; off; off >>= 1) v += __shfl_down(v, off, 64);
    __shared__ float red[4];
    if ((t & 63) == 0) red[t >> 6] = v;
    __syncthreads();
    float s = red[0] + red[1] + red[2] + red[3];
    if (t < KTAP) w_out[o*KTAP + t] = myv / (s + EPSV);
}

// ---------------------------------------------------------------------------
// LN (channels-first, eps 1e-6) -> relu -> x / (sum_c x + EPS)  => X
__global__ void ln1_kernel(const float* __restrict__ x, const float* __restrict__ lw,
                           const float* __restrict__ lb, float* __restrict__ X) {
    int p = blockIdx.x * blockDim.x + threadIdx.x;
    if (p >= NPIX) return;
    int n = p / HWHW, hw = p % HWHW;
    const float* xp = x + (size_t)n*CC_*HWHW + hw;
    float s = 0.f, ss = 0.f;
    for (int c = 0; c < CC_; ++c) { float v = xp[(size_t)c*HWHW]; s += v; ss += v*v; }
    float u  = s * (1.f/CC_);
    float var = ss * (1.f/CC_) - u*u;
    float rs = rsqrtf(var + 1e-6f);
    float sr = 0.f;
    for (int c = 0; c < CC_; ++c) {
        float v = xp[(size_t)c*HWHW];
        float a = fmaxf((v-u)*rs*lw[c] + lb[c], 0.f);
        sr += a;
    }
    float inv = 1.f / (sr + EPSV);
    float* Xp = X + (size_t)n*CC_*HWHW + hw;
    for (int c = 0; c < CC_; ++c) {
        float v = xp[(size_t)c*HWHW];
        float a = fmaxf((v-u)*rs*lw[c] + lb[c], 0.f);
        Xp[(size_t)c*HWHW] = a * inv;
    }
}

// ---------------------------------------------------------------------------
__global__ void fill_kernel(float* __restrict__ p, int n, float v) {
    int i = blockIdx.x * blockDim.x + threadIdx.x;
    if (i < n) p[i] = v;
}

// ---------------------------------------------------------------------------
// Grouped 3x3 conv (pad 1), 24->24 channels per group.
// FLIP=false: out[oc] = sum_{ic,ky,kx} in[ic, y+ky-1, x+kx-1] * W[(g*24+oc)*216 + ic*9+ky*3+kx]
// FLIP=true (transposed conv): weight = W[(g*24+ic)*216 + oc*9 + (8 - (ky*3+kx))]
// EPI=0: out = X / (acc + EPS)   (ratio);  EPI=1: out *= acc  (multiplicative update)
template<bool FLIP, int EPI>
__global__ __launch_bounds__(448) void conv_kernel(const float* __restrict__ in,
                                                   const float* __restrict__ W,
                                                   const float* __restrict__ X,
                                                   float* __restrict__ out) {
    __shared__ float lin[IG*6*58];      // [ic][6 rows][58 cols]  (33.4 KB)
    __shared__ float lw[KTAP*IG];       // [tap][oc]              (20.7 KB)
    int b   = blockIdx.x;               // 8*4*14 = 448
    int rt  = b % 14;
    int g   = (b / 14) % GROUPS;
    int n   = b / 56;
    int tid = threadIdx.x;

    // stage weights, layout lw[tap*24 + oc]
    for (int idx = tid; idx < KTAP*IG; idx += 448) {
        int tap = idx / IG, oc = idx % IG;
        float wv;
        if (FLIP) {
            int ict = tap / 9, koff = tap % 9;
            wv = W[(size_t)(g*IG + ict)*KTAP + oc*9 + (8 - koff)];
        } else {
            wv = W[(size_t)(g*IG + oc)*KTAP + tap];
        }
        lw[idx] = wv;
    }
    // stage input tile: channels of this group, rows rt*4-1 .. rt*4+4, cols -1..56
    const float* inb = in + ((size_t)n*CC_ + g*IG) * HWHW;
    int r0 = rt*4 - 1;
    for (int idx = tid; idx < IG*6*58; idx += 448) {
        int ic  = idx / 348;
        int rem = idx % 348;
        int r   = rem / 58, cc = rem % 58;
        int gr = r0 + r, gc = cc - 1;
        float v = 0.f;
        if (gr >= 0 && gr < HH && gc >= 0 && gc < WW)
            v = inb[(size_t)ic*HWHW + gr*WW + gc];
        lin[idx] = v;
    }
    __syncthreads();

    // compute: thread -> 4 consecutive x pixels, 1 row, 3 output channels
    int x4  = tid % 14;
    int row = (tid / 14) % 4;
    int og  = tid / 56;      // 0..7
    int x0  = x4 * 4;
    int ocb = og * 3;
    float acc[3][4] = {};
    for (int ic = 0; ic < IG; ++ic) {
        #pragma unroll
        for (int ky = 0; ky < 3; ++ky) {
            const float* ir = &lin[ic*348 + (row+ky)*58 + x0];
            float vv[6];
            #pragma unroll
            for (int j = 0; j < 6; ++j) vv[j] = ir[j];
            #pragma unroll
            for (int kx = 0; kx < 3; ++kx) {
                const float* wp = &lw[(ic*9 + ky*3 + kx)*IG + ocb];
                #pragma unroll
                for (int o = 0; o < 3; ++o) {
                    float wv = wp[o];
                    #pragma unroll
                    for (int p = 0; p < 4; ++p)
                        acc[o][p] = fmaf(vv[kx+p], wv, acc[o][p]);
                }
            }
        }
    }
    int grow = rt*4 + row;
    size_t base = ((size_t)n*CC_ + g*IG + ocb) * HWHW + grow*WW + x0;
    #pragma unroll
    for (int o = 0; o < 3; ++o) {
        size_t bo = base + (size_t)o*HWHW;
        #pragma unroll
        for (int p = 0; p < 4; ++p) {
            float a = acc[o][p];
            if (EPI == 0) out[bo+p] = X[bo+p] / (a + EPSV);
            else          out[bo+p] = out[bo+p] * a;
        }
    }
}

// ---------------------------------------------------------------------------
// h /= (sum_c h + EPS) per pixel
__global__ void hnorm_kernel(float* __restrict__ H) {
    int p = blockIdx.x * blockDim.x + threadIdx.x;
    if (p >= NPIX) return;
    int n = p / HWHW, hw = p % HWHW;
    float* hp = H + (size_t)n*CC_*HWHW + hw;
    float s = 0.f;
    for (int c = 0; c < CC_; ++c) s += hp[(size_t)c*HWHW];
    float inv = 1.f / (s + EPSV);
    for (int c = 0; c < CC_; ++c) hp[(size_t)c*HWHW] *= inv;
}

// ---------------------------------------------------------------------------
// x2 = x + H -> d_out ; XLN = LN(x2) (over C, eps 1e-5) -> R
__global__ void resln2_kernel(const float* __restrict__ x, const float* __restrict__ H,
                              const float* __restrict__ lw, const float* __restrict__ lb,
                              float* __restrict__ out, float* __restrict__ XLN) {
    int p = blockIdx.x * blockDim.x + threadIdx.x;
    if (p >= NPIX) return;
    int n = p / HWHW, hw = p % HWHW;
    size_t base = (size_t)n*CC_*HWHW + hw;
    float s = 0.f, ss = 0.f;
    for (int c = 0; c < CC_; ++c) {
        float v = x[base + (size_t)c*HWHW] + H[base + (size_t)c*HWHW];
        out[base + (size_t)c*HWHW] = v;
        s += v; ss += v*v;
    }
    float u  = s * (1.f/CC_);
    float var = ss * (1.f/CC_) - u*u;
    float rs = rsqrtf(var + 1e-5f);
    for (int c = 0; c < CC_; ++c) {
        float v = out[base + (size_t)c*HWHW];
        XLN[base + (size_t)c*HWHW] = (v-u)*rs*lw[c] + lb[c];
    }
}

// ---------------------------------------------------------------------------
// Fused MLP: out += gelu(XLN @ w1 + b1) @ w2 + b2   (32 tokens per block)
__global__ __launch_bounds__(384) void mlp_kernel(const float* __restrict__ XLN,
                                                  const float* __restrict__ w1,
                                                  const float* __restrict__ b1,
                                                  const float* __restrict__ w2,
                                                  const float* __restrict__ b2,
                                                  float* __restrict__ out) {
    __shared__ float lx[32*97];          // [t][c] padded
    __shared__ float lh[32*388];         // [t][j] padded
    int blk = blockIdx.x;                // 784
    int tid = threadIdx.x;               // 384
    int p0  = blk * 32;
    int n   = p0 / HWHW;                 // 32 | 3136, so tile stays in one n
    int hw0 = p0 % HWHW;
    const float* Xb = XLN + (size_t)n*CC_*HWHW + hw0;
    for (int idx = tid; idx < 32*CC_; idx += 384) {
        int c = idx / 32, t = idx % 32;
        lx[t*97 + c] = Xb[(size_t)c*HWHW + t];
    }
    __syncthreads();

    // GEMM1: 32x96 @ 96x384, thread tile 4 tokens x 8 hidden
    int tg = tid / 48, jg = tid % 48;
    int t0 = tg * 4, j0 = jg * 8;
    float acc1[4][8] = {};
    for (int k = 0; k < CC_; ++k) {
        float a0 = lx[(t0+0)*97 + k];
        float a1 = lx[(t0+1)*97 + k];
        float a2 = lx[(t0+2)*97 + k];
        float a3 = lx[(t0+3)*97 + k];
        const float* wp = w1 + (size_t)k*384 + j0;
        #pragma unroll
        for (int j = 0; j < 8; ++j) {
            float wv = wp[j];
            acc1[0][j] = fmaf(a0, wv, acc1[0][j]);
            acc1[1][j] = fmaf(a1, wv, acc1[1][j]);
            acc1[2][j] = fmaf(a2, wv, acc1[2][j]);
            acc1[3][j] = fmaf(a3, wv, acc1[3][j]);
        }
    }
    #pragma unroll
    for (int i = 0; i < 4; ++i) {
        #pragma unroll
        for (int j = 0; j < 8; ++j) {
            float h = acc1[i][j] + b1[j0 + j];
            h = 0.5f * h * (1.f + erff(h * 0.70710678118654752440f));
            lh[(t0+i)*388 + j0 + j] = h;
        }
    }
    __syncthreads();

    // GEMM2: 32x384 @ 384x96, thread: 1 channel x 8 tokens
    int c  = tid % CC_;
    int tq = tid / CC_;                  // 0..3
    float acc2[8] = {};
    for (int k = 0; k < 384; ++k) {
        float wv = w2[(size_t)k*CC_ + c];
        #pragma unroll
        for (int i = 0; i < 8; ++i)
            acc2[i] = fmaf(lh[(tq*8+i)*388 + k], wv, acc2[i]);
    }
    float bv = b2[c];
    size_t obase = ((size_t)n*CC_ + c)*HWHW + hw0;
    #pragma unroll
    for (int i = 0; i < 8; ++i) {
        int t = tq*8 + i;
        out[obase + t] += acc2[i] + bv;
    }
}

// ---------------------------------------------------------------------------
extern "C" void kernel_launch(void* const* d_in, const int* in_sizes, int n_in,
                              void* d_out, int out_size, void* d_ws, size_t ws_size,
                              hipStream_t stream) {
    const float* x    = (const float*)d_in[0];
    const float* ln1w = (const float*)d_in[1];
    const float* ln1b = (const float*)d_in[2];
    const float* wnn  = (const float*)d_in[3];
    const float* ln2w = (const float*)d_in[4];
    const float* ln2b = (const float*)d_in[5];
    const float* w1   = (const float*)d_in[6];
    const float* b1   = (const float*)d_in[7];
    const float* w2   = (const float*)d_in[8];
    const float* b2   = (const float*)d_in[9];
    float* out = (float*)d_out;
    float* ws  = (float*)d_ws;

    float* Wn = ws;                       // 20736
    float* X  = Wn + 20736;               // 2408448
    float* H  = X  + NELEM;               // 2408448
    float* R  = H  + NELEM;               // 2408448 (ratio, later XLN)

    wnorm_kernel<<<CC_, 256, 0, stream>>>(wnn, Wn);
    ln1_kernel<<<NPIX/256, 256, 0, stream>>>(x, ln1w, ln1b, X);
    fill_kernel<<<(NELEM+255)/256, 256, 0, stream>>>(H, NELEM, 1.f/CC_);

    for (int it = 0; it < NITER; ++it) {
        conv_kernel<true, 0><<<448, 448, 0, stream>>>(H, Wn, X, R);  // R = X/(reconT(H)+EPS)
        conv_kernel<false, 1><<<448, 448, 0, stream>>>(R, Wn, nullptr, H); // H *= conv(R)
        hnorm_kernel<<<NPIX/256, 256, 0, stream>>>(H);
    }

    resln2_kernel<<<NPIX/256, 256, 0, stream>>>(x, H, ln2w, ln2b, out, R);
    mlp_kernel<<<NPIX/32, 384, 0, stream>>>(R, w1, b1, w2, b2, out);
}

// Round 2
// 2113.124 us; speedup vs baseline: 1.3184x; 1.3184x over previous
//
#include <hip/hip_runtime.h>
#include <math.h>

// Problem constants
#define NN    8
#define CC_   96
#define HH    56
#define WW    56
#define HWHW  (HH*WW)            // 3136
#define NPIX  (NN*HWHW)          // 25088
#define NELEM (NN*CC_*HWHW)      // 2408448
#define GROUPS 4
#define IG    24                 // channels per group
#define KTAP  216                // 24*9
#define NITER 25
#define EPSV  1e-12f

// Packed weight chunk: per (g,ocg,ic) 9 taps x 6 oc = 54 floats, padded to 56.
#define WCHUNK 56
#define WTOTAL (GROUPS*4*IG*WCHUNK)   // 21504

// ---------------------------------------------------------------------------
// Normalize weights and pack into BOTH conv layouts:
//  Wf (forward conv):  Wf[((g*4+ocg)*24+ic)*56 + tap*6 + oo]  = wn[o=g*24+ocg*6+oo][ic*9+tap]
//  Wt (transposed):    Wt[((g*4+ic/6)*24+ol)*56 + (8-k)*6 + ic%6] = wn[o][ic*9+k]
__global__ void wnorm2_kernel(const float* __restrict__ w_in,
                              float* __restrict__ Wf, float* __restrict__ Wt) {
    int o = blockIdx.x;          // 96
    int t = threadIdx.x;         // 256
    float myv = (t < KTAP) ? fabsf(w_in[o*KTAP + t]) : 0.f;
    float v = myv;
    #pragma unroll
    for (int off = 32; off; off >>= 1) v += __shfl_down(v, off, 64);
    __shared__ float red[4];
    if ((t & 63) == 0) red[t >> 6] = v;
    __syncthreads();
    float s = red[0] + red[1] + red[2] + red[3];
    if (t < KTAP) {
        float w = myv / (s + EPSV);
        int ic = t / 9, k = t % 9;
        int g  = o / IG, ol = o % IG;
        Wf[((g*4 + ol/6)*IG + ic)*WCHUNK + k*6 + (ol%6)] = w;
        Wt[((g*4 + ic/6)*IG + ol)*WCHUNK + (8-k)*6 + (ic%6)] = w;
    }
}

// ---------------------------------------------------------------------------
// LN (channels-first, eps 1e-6) -> relu -> x / (sum_c x + EPS)  => X
__global__ void ln1_kernel(const float* __restrict__ x, const float* __restrict__ lw,
                           const float* __restrict__ lb, float* __restrict__ X) {
    int p = blockIdx.x * blockDim.x + threadIdx.x;
    if (p >= NPIX) return;
    int n = p / HWHW, hw = p % HWHW;
    const float* xp = x + (size_t)n*CC_*HWHW + hw;
    float s = 0.f, ss = 0.f;
    for (int c = 0; c < CC_; ++c) { float v = xp[(size_t)c*HWHW]; s += v; ss += v*v; }
    float u  = s * (1.f/CC_);
    float var = ss * (1.f/CC_) - u*u;
    float rs = rsqrtf(var + 1e-6f);
    float sr = 0.f;
    for (int c = 0; c < CC_; ++c) {
        float v = xp[(size_t)c*HWHW];
        float a = fmaxf((v-u)*rs*lw[c] + lb[c], 0.f);
        sr += a;
    }
    float inv = 1.f / (sr + EPSV);
    float* Xp = X + (size_t)n*CC_*HWHW + hw;
    for (int c = 0; c < CC_; ++c) {
        float v = xp[(size_t)c*HWHW];
        float a = fmaxf((v-u)*rs*lw[c] + lb[c], 0.f);
        Xp[(size_t)c*HWHW] = a * inv;
    }
}

// ---------------------------------------------------------------------------
__global__ void fill_kernel(float* __restrict__ p, int n, float v) {
    int i = blockIdx.x * blockDim.x + threadIdx.x;
    if (i < n) p[i] = v;
}

// ---------------------------------------------------------------------------
// Grouped 3x3 conv (pad 1), 24->24 per group, packed per-ocg weights.
// Block: 256 thr = 4 waves (one oc-group of 6 each); covers (n, g, 4-row band).
// Lane (0..55): xt = lane%14 (4 px), row = lane/14.
// EPI==0 (convT / ratio step): stages Hu/(Scur+EPS); zeroes its slice of Snxt;
//                              out = X / (acc + EPS)            -> R
// EPI==1 (multiplicative step): stages in raw (ratio R);
//                              h = Hu/(Scur+EPS) * acc; Hu = h; atomicAdd Snxt += sum_c h
template<int EPI>
__global__ __launch_bounds__(256) void conv2_kernel(const float* __restrict__ in,
                                                    const float* __restrict__ W,
                                                    const float* __restrict__ X,
                                                    const float* __restrict__ Scur,
                                                    float* __restrict__ Snxt,
                                                    float* __restrict__ Hu,
                                                    float* __restrict__ out) {
    __shared__ float lin[IG*6*60];      // [ic][6 rows][60 (58 used, halo-shifted)] 34.6 KB
    int b   = blockIdx.x;               // 8*4*14 = 448
    int rt  = b % 14;
    int g   = (b / 14) % GROUPS;
    int n   = b / 56;
    int tid = threadIdx.x;

    if (EPI == 0) {   // zero next-S (448*56 == 25088)
        if (tid < 56) Snxt[b*56 + tid] = 0.f;
    }

    // stage input tile: rows rt*4-1 .. rt*4+4 (6), cols -1..56 stored at pos 0..57
    const float* inb = in + ((size_t)n*CC_ + g*IG) * HWHW;
    const float* Sb  = Scur + n*HWHW;
    int r0 = rt*4 - 1;
    for (int idx = tid; idx < IG*6*58; idx += 256) {
        int ic  = idx / 348;
        int rem = idx % 348;
        int r   = rem / 58, pos = rem % 58;
        int gr = r0 + r, gc = pos - 1;
        float v = 0.f;
        if (gr >= 0 && gr < HH && gc >= 0 && gc < WW) {
            v = inb[(size_t)ic*HWHW + gr*WW + gc];
            if (EPI == 0) v = v / (Sb[gr*WW + gc] + EPSV);
        }
        lin[ic*360 + r*60 + pos] = v;
    }
    __syncthreads();

    int lane = tid & 63;
    int ocg  = tid >> 6;                 // 0..3
    if (lane >= 56) return;
    int xt  = lane % 14;
    int row = lane / 14;                 // 0..3
    int x0  = xt * 4;

    const float* Wc = W + (size_t)((g*4 + ocg)*IG) * WCHUNK;

    float acc[6][4] = {};
    #pragma unroll 1
    for (int ic = 0; ic < IG; ++ic) {
        union { float4 q[14]; float f[56]; } wq;
        const float4* wp = (const float4*)(Wc + ic*WCHUNK);
        #pragma unroll
        for (int j = 0; j < 14; ++j) wq.q[j] = wp[j];

        const float* lb = &lin[ic*360 + row*60 + x0];
        float v[3][6];
        #pragma unroll
        for (int ky = 0; ky < 3; ++ky) {
            float4 a = *(const float4*)(lb + ky*60);
            float2 c2 = *(const float2*)(lb + ky*60 + 4);
            v[ky][0]=a.x; v[ky][1]=a.y; v[ky][2]=a.z; v[ky][3]=a.w;
            v[ky][4]=c2.x; v[ky][5]=c2.y;
        }
        #pragma unroll
        for (int ky = 0; ky < 3; ++ky)
            #pragma unroll
            for (int kx = 0; kx < 3; ++kx) {
                const int tap = ky*3 + kx;
                #pragma unroll
                for (int o = 0; o < 6; ++o) {
                    float wv = wq.f[tap*6 + o];
                    #pragma unroll
                    for (int p = 0; p < 4; ++p)
                        acc[o][p] = fmaf(v[ky][kx+p], wv, acc[o][p]);
                }
            }
    }

    int grow = rt*4 + row;
    size_t obase = ((size_t)n*CC_ + g*IG + ocg*6) * HWHW + grow*WW + x0;

    if (EPI == 0) {
        #pragma unroll
        for (int o = 0; o < 6; ++o) {
            size_t bo = obase + (size_t)o*HWHW;
            float4 xx = *(const float4*)(X + bo);
            float4 r;
            r.x = xx.x / (acc[o][0] + EPSV);
            r.y = xx.y / (acc[o][1] + EPSV);
            r.z = xx.z / (acc[o][2] + EPSV);
            r.w = xx.w / (acc[o][3] + EPSV);
            *(float4*)(out + bo) = r;
        }
    } else {
        int pix = n*HWHW + grow*WW + x0;
        float4 sv = *(const float4*)(Scur + pix);
        float inv0 = 1.f / (sv.x + EPSV);
        float inv1 = 1.f / (sv.y + EPSV);
        float inv2 = 1.f / (sv.z + EPSV);
        float inv3 = 1.f / (sv.w + EPSV);
        float ps0 = 0.f, ps1 = 0.f, ps2 = 0.f, ps3 = 0.f;
        #pragma unroll
        for (int o = 0; o < 6; ++o) {
            size_t bo = obase + (size_t)o*HWHW;
            float4 hu = *(const float4*)(Hu + bo);
            float4 h;
            h.x = hu.x * inv0 * acc[o][0];
            h.y = hu.y * inv1 * acc[o][1];
            h.z = hu.z * inv2 * acc[o][2];
            h.w = hu.w * inv3 * acc[o][3];
            *(float4*)(Hu + bo) = h;
            ps0 += h.x; ps1 += h.y; ps2 += h.z; ps3 += h.w;
        }
        atomicAdd(&Snxt[pix+0], ps0);
        atomicAdd(&Snxt[pix+1], ps1);
        atomicAdd(&Snxt[pix+2], ps2);
        atomicAdd(&Snxt[pix+3], ps3);
    }
}

// ---------------------------------------------------------------------------
// x2 = x + Hu/(S+EPS) -> d_out ; XLN = LN(x2) (over C, eps 1e-5) -> R
__global__ void resln2_kernel(const float* __restrict__ x, const float* __restrict__ Hu,
                              const float* __restrict__ S,
                              const float* __restrict__ lw, const float* __restrict__ lb,
                              float* __restrict__ out, float* __restrict__ XLN) {
    int p = blockIdx.x * blockDim.x + threadIdx.x;
    if (p >= NPIX) return;
    int n = p / HWHW, hw = p % HWHW;
    size_t base = (size_t)n*CC_*HWHW + hw;
    float sinv = 1.f / (S[p] + EPSV);
    float s = 0.f, ss = 0.f;
    for (int c = 0; c < CC_; ++c) {
        float v = x[base + (size_t)c*HWHW] + Hu[base + (size_t)c*HWHW] * sinv;
        out[base + (size_t)c*HWHW] = v;
        s += v; ss += v*v;
    }
    float u  = s * (1.f/CC_);
    float var = ss * (1.f/CC_) - u*u;
    float rs = rsqrtf(var + 1e-5f);
    for (int c = 0; c < CC_; ++c) {
        float v = out[base + (size_t)c*HWHW];
        XLN[base + (size_t)c*HWHW] = (v-u)*rs*lw[c] + lb[c];
    }
}

// ---------------------------------------------------------------------------
// Fused MLP: out += gelu(XLN @ w1 + b1) @ w2 + b2   (32 tokens per block)
__global__ __launch_bounds__(384) void mlp_kernel(const float* __restrict__ XLN,
                                                  const float* __restrict__ w1,
                                                  const float* __restrict__ b1,
                                                  const float* __restrict__ w2,
                                                  const float* __restrict__ b2,
                                                  float* __restrict__ out) {
    __shared__ float lx[32*97];          // [t][c] padded
    __shared__ float lh[32*388];         // [t][j] padded
    int blk = blockIdx.x;                // 784
    int tid = threadIdx.x;               // 384
    int p0  = blk * 32;
    int n   = p0 / HWHW;
    int hw0 = p0 % HWHW;
    const float* Xb = XLN + (size_t)n*CC_*HWHW + hw0;
    for (int idx = tid; idx < 32*CC_; idx += 384) {
        int c = idx / 32, t = idx % 32;
        lx[t*97 + c] = Xb[(size_t)c*HWHW + t];
    }
    __syncthreads();

    int tg = tid / 48, jg = tid % 48;
    int t0 = tg * 4, j0 = jg * 8;
    float acc1[4][8] = {};
    for (int k = 0; k < CC_; ++k) {
        float a0 = lx[(t0+0)*97 + k];
        float a1 = lx[(t0+1)*97 + k];
        float a2 = lx[(t0+2)*97 + k];
        float a3 = lx[(t0+3)*97 + k];
        const float* wp = w1 + (size_t)k*384 + j0;
        #pragma unroll
        for (int j = 0; j < 8; ++j) {
            float wv = wp[j];
            acc1[0][j] = fmaf(a0, wv, acc1[0][j]);
            acc1[1][j] = fmaf(a1, wv, acc1[1][j]);
            acc1[2][j] = fmaf(a2, wv, acc1[2][j]);
            acc1[3][j] = fmaf(a3, wv, acc1[3][j]);
        }
    }
    #pragma unroll
    for (int i = 0; i < 4; ++i) {
        #pragma unroll
        for (int j = 0; j < 8; ++j) {
            float h = acc1[i][j] + b1[j0 + j];
            h = 0.5f * h * (1.f + erff(h * 0.70710678118654752440f));
            lh[(t0+i)*388 + j0 + j] = h;
        }
    }
    __syncthreads();

    int c  = tid % CC_;
    int tq = tid / CC_;
    float acc2[8] = {};
    for (int k = 0; k < 384; ++k) {
        float wv = w2[(size_t)k*CC_ + c];
        #pragma unroll
        for (int i = 0; i < 8; ++i)
            acc2[i] = fmaf(lh[(tq*8+i)*388 + k], wv, acc2[i]);
    }
    float bv = b2[c];
    size_t obase = ((size_t)n*CC_ + c)*HWHW + hw0;
    #pragma unroll
    for (int i = 0; i < 8; ++i) {
        int t = tq*8 + i;
        out[obase + t] += acc2[i] + bv;
    }
}

// ---------------------------------------------------------------------------
extern "C" void kernel_launch(void* const* d_in, const int* in_sizes, int n_in,
                              void* d_out, int out_size, void* d_ws, size_t ws_size,
                              hipStream_t stream) {
    const float* x    = (const float*)d_in[0];
    const float* ln1w = (const float*)d_in[1];
    const float* ln1b = (const float*)d_in[2];
    const float* wnn  = (const float*)d_in[3];
    const float* ln2w = (const float*)d_in[4];
    const float* ln2b = (const float*)d_in[5];
    const float* w1   = (const float*)d_in[6];
    const float* b1   = (const float*)d_in[7];
    const float* w2   = (const float*)d_in[8];
    const float* b2   = (const float*)d_in[9];
    float* out = (float*)d_out;
    float* ws  = (float*)d_ws;

    float* Wf = ws;                       // 21504
    float* Wt = Wf + WTOTAL;              // 21504
    float* X  = Wt + WTOTAL;              // NELEM
    float* Hu = X  + NELEM;               // NELEM
    float* R  = Hu + NELEM;               // NELEM (ratio, later XLN)
    float* S0 = R  + NELEM;               // NPIX
    float* S1 = S0 + NPIX;                // NPIX

    wnorm2_kernel<<<CC_, 256, 0, stream>>>(wnn, Wf, Wt);
    ln1_kernel<<<NPIX/256, 256, 0, stream>>>(x, ln1w, ln1b, X);
    fill_kernel<<<NELEM/256, 256, 0, stream>>>(Hu, NELEM, 1.f/CC_);
    fill_kernel<<<NPIX/256, 256, 0, stream>>>(S0, NPIX, 1.f);

    for (int it = 0; it < NITER; ++it) {
        float* Scur = (it & 1) ? S1 : S0;
        float* Snxt = (it & 1) ? S0 : S1;
        // R = X / (convT(Hu/S) + EPS); also zeroes Snxt
        conv2_kernel<0><<<448, 256, 0, stream>>>(Hu, Wt, X, Scur, Snxt, nullptr, R);
        // Hu = (Hu/S) * conv(R); Snxt += channel sums
        conv2_kernel<1><<<448, 256, 0, stream>>>(R, Wf, nullptr, Scur, Snxt, Hu, nullptr);
    }
    float* Sfin = S1;  // 25 iters: last writes S1 (it=24 even -> Snxt=S1)

    resln2_kernel<<<NPIX/256, 256, 0, stream>>>(x, Hu, Sfin, ln2w, ln2b, out, R);
    mlp_kernel<<<NPIX/32, 384, 0, stream>>>(R, w1, b1, w2, b2, out);
}

// Round 3
// 1497.796 us; speedup vs baseline: 1.8600x; 1.4108x over previous
//
#include <hip/hip_runtime.h>
#include <math.h>

// Problem constants
#define NN    8
#define CC_   96
#define HH    56
#define WW    56
#define HWHW  (HH*WW)            // 3136
#define NPIX  (NN*HWHW)          // 25088
#define NELEM (NN*CC_*HWHW)      // 2408448
#define GROUPS 4
#define IG    24                 // channels per group
#define KTAP  216                // 24*9
#define NITER 25
#define EPSV  1e-12f

// Packed weight chunk: per (g,ocg,ic) 9 taps x 6 oc = 54 floats, padded to 56.
#define WCHUNK 56
#define WTOTAL (GROUPS*4*IG*WCHUNK)   // 21504

// ---------------------------------------------------------------------------
// Normalize weights and pack into BOTH conv layouts:
//  Wf (forward conv):  Wf[((g*4+ocg)*24+ic)*56 + tap*6 + oo]  = wn[o=g*24+ocg*6+oo][ic*9+tap]
//  Wt (transposed):    Wt[((g*4+ic/6)*24+ol)*56 + (8-k)*6 + ic%6] = wn[o][ic*9+k]
__global__ void wnorm2_kernel(const float* __restrict__ w_in,
                              float* __restrict__ Wf, float* __restrict__ Wt) {
    int o = blockIdx.x;          // 96
    int t = threadIdx.x;         // 256
    float myv = (t < KTAP) ? fabsf(w_in[o*KTAP + t]) : 0.f;
    float v = myv;
    #pragma unroll
    for (int off = 32; off; off >>= 1) v += __shfl_down(v, off, 64);
    __shared__ float red[4];
    if ((t & 63) == 0) red[t >> 6] = v;
    __syncthreads();
    float s = red[0] + red[1] + red[2] + red[3];
    if (t < KTAP) {
        float w = myv / (s + EPSV);
        int ic = t / 9, k = t % 9;
        int g  = o / IG, ol = o % IG;
        Wf[((g*4 + ol/6)*IG + ic)*WCHUNK + k*6 + (ol%6)] = w;
        Wt[((g*4 + ic/6)*IG + ol)*WCHUNK + (8-k)*6 + (ic%6)] = w;
    }
}

// ---------------------------------------------------------------------------
// LN (channels-first, eps 1e-6) -> relu -> x / (sum_c x + EPS)  => X
__global__ void ln1_kernel(const float* __restrict__ x, const float* __restrict__ lw,
                           const float* __restrict__ lb, float* __restrict__ X) {
    int p = blockIdx.x * blockDim.x + threadIdx.x;
    if (p >= NPIX) return;
    int n = p / HWHW, hw = p % HWHW;
    const float* xp = x + (size_t)n*CC_*HWHW + hw;
    float s = 0.f, ss = 0.f;
    for (int c = 0; c < CC_; ++c) { float v = xp[(size_t)c*HWHW]; s += v; ss += v*v; }
    float u  = s * (1.f/CC_);
    float var = ss * (1.f/CC_) - u*u;
    float rs = rsqrtf(var + 1e-6f);
    float sr = 0.f;
    for (int c = 0; c < CC_; ++c) {
        float v = xp[(size_t)c*HWHW];
        float a = fmaxf((v-u)*rs*lw[c] + lb[c], 0.f);
        sr += a;
    }
    float inv = 1.f / (sr + EPSV);
    float* Xp = X + (size_t)n*CC_*HWHW + hw;
    for (int c = 0; c < CC_; ++c) {
        float v = xp[(size_t)c*HWHW];
        float a = fmaxf((v-u)*rs*lw[c] + lb[c], 0.f);
        Xp[(size_t)c*HWHW] = a * inv;
    }
}

// ---------------------------------------------------------------------------
__global__ void fill_kernel(float* __restrict__ p, int n, float v) {
    int i = blockIdx.x * blockDim.x + threadIdx.x;
    if (i < n) p[i] = v;
}

// ---------------------------------------------------------------------------
// Grouped 3x3 conv (pad 1), 24->24 per group.
// Block: 512 thr = 8 waves; wave = (ocg 0..3 [6 oc each], rp 0..1 [2 rows each]).
// Lane (<56): xt = lane%28 (2 px), row2 = lane/28; row = rp*2+row2.
// EPI==0 (convT / ratio): stages Hu/(Scur+EPS); zeroes Snxt slice; out = X/(acc+EPS)
// EPI==1 (mult update):   stages R raw; h = Hu/(Scur+EPS)*acc; Hu=h; Snxt += sum_c h
template<int EPI>
__global__ __launch_bounds__(512, 4) void conv3_kernel(const float* __restrict__ in,
                                                       const float* __restrict__ W,
                                                       const float* __restrict__ X,
                                                       const float* __restrict__ Scur,
                                                       float* __restrict__ Snxt,
                                                       float* __restrict__ Hu,
                                                       float* __restrict__ out) {
    __shared__ float lin[IG*6*60];      // [ic][6 rows][60 (58 used)] 34.6 KB
    int b   = blockIdx.x;               // 8*4*14 = 448
    int rt  = b % 14;
    int g   = (b / 14) % GROUPS;
    int n   = b / 56;
    int tid = threadIdx.x;

    if (EPI == 0) {   // zero next-S (448*56 == 25088)
        if (tid < 56) Snxt[b*56 + tid] = 0.f;
    }

    // stage input tile: rows rt*4-1 .. rt*4+4 (6), cols -1..56 stored at 0..57
    const float* inb = in + ((size_t)n*CC_ + g*IG) * HWHW;
    const float* Sb  = Scur + n*HWHW;
    int r0 = rt*4 - 1;
    for (int idx = tid; idx < IG*6*58; idx += 512) {
        int ic  = idx / 348;
        int rem = idx % 348;
        int r   = rem / 58, pos = rem % 58;
        int gr = r0 + r, gc = pos - 1;
        float v = 0.f;
        if (gr >= 0 && gr < HH && gc >= 0 && gc < WW) {
            v = inb[(size_t)ic*HWHW + gr*WW + gc];
            if (EPI == 0) v = v / (Sb[gr*WW + gc] + EPSV);
        }
        lin[ic*360 + r*60 + pos] = v;
    }
    __syncthreads();

    int waveId = __builtin_amdgcn_readfirstlane(tid >> 6);   // uniform
    int ocg = waveId & 3;
    int rp  = waveId >> 2;
    int lane = tid & 63;
    if (lane >= 56) return;
    int xt   = lane % 28;
    int row2 = lane / 28;
    int row  = rp*2 + row2;              // 0..3
    int x0   = xt * 2;

    const float* Wc = W + (size_t)((g*4 + ocg)*IG) * WCHUNK;   // wave-uniform

    float acc[6][2] = {};
    #pragma unroll 1
    for (int ic = 0; ic < IG; ++ic) {
        union { float4 q[14]; float f[56]; } wq;
        const float4* wp = (const float4*)(Wc + ic*WCHUNK);
        #pragma unroll
        for (int j = 0; j < 14; ++j) wq.q[j] = wp[j];

        const float* lb = &lin[ic*360 + row*60 + x0];
        float v[3][4];
        #pragma unroll
        for (int ky = 0; ky < 3; ++ky) {
            float2 a = *(const float2*)(lb + ky*60);
            float2 c2 = *(const float2*)(lb + ky*60 + 2);
            v[ky][0]=a.x; v[ky][1]=a.y; v[ky][2]=c2.x; v[ky][3]=c2.y;
        }
        #pragma unroll
        for (int ky = 0; ky < 3; ++ky)
            #pragma unroll
            for (int kx = 0; kx < 3; ++kx) {
                const int tap = ky*3 + kx;
                #pragma unroll
                for (int o = 0; o < 6; ++o) {
                    float wv = wq.f[tap*6 + o];
                    acc[o][0] = fmaf(v[ky][kx+0], wv, acc[o][0]);
                    acc[o][1] = fmaf(v[ky][kx+1], wv, acc[o][1]);
                }
            }
    }

    int grow = rt*4 + row;
    size_t obase = ((size_t)n*CC_ + g*IG + ocg*6) * HWHW + grow*WW + x0;

    if (EPI == 0) {
        #pragma unroll
        for (int o = 0; o < 6; ++o) {
            size_t bo = obase + (size_t)o*HWHW;
            float2 xx = *(const float2*)(X + bo);
            float2 r;
            r.x = xx.x / (acc[o][0] + EPSV);
            r.y = xx.y / (acc[o][1] + EPSV);
            *(float2*)(out + bo) = r;
        }
    } else {
        int pix = n*HWHW + grow*WW + x0;
        float2 sv = *(const float2*)(Scur + pix);
        float inv0 = 1.f / (sv.x + EPSV);
        float inv1 = 1.f / (sv.y + EPSV);
        float ps0 = 0.f, ps1 = 0.f;
        #pragma unroll
        for (int o = 0; o < 6; ++o) {
            size_t bo = obase + (size_t)o*HWHW;
            float2 hu = *(const float2*)(Hu + bo);
            float2 h;
            h.x = hu.x * inv0 * acc[o][0];
            h.y = hu.y * inv1 * acc[o][1];
            *(float2*)(Hu + bo) = h;
            ps0 += h.x; ps1 += h.y;
        }
        atomicAdd(&Snxt[pix+0], ps0);
        atomicAdd(&Snxt[pix+1], ps1);
    }
}

// ---------------------------------------------------------------------------
// x2 = x + Hu/(S+EPS) -> d_out ; XLN = LN(x2) (over C, eps 1e-5) -> R
__global__ void resln2_kernel(const float* __restrict__ x, const float* __restrict__ Hu,
                              const float* __restrict__ S,
                              const float* __restrict__ lw, const float* __restrict__ lb,
                              float* __restrict__ out, float* __restrict__ XLN) {
    int p = blockIdx.x * blockDim.x + threadIdx.x;
    if (p >= NPIX) return;
    int n = p / HWHW, hw = p % HWHW;
    size_t base = (size_t)n*CC_*HWHW + hw;
    float sinv = 1.f / (S[p] + EPSV);
    float s = 0.f, ss = 0.f;
    for (int c = 0; c < CC_; ++c) {
        float v = x[base + (size_t)c*HWHW] + Hu[base + (size_t)c*HWHW] * sinv;
        out[base + (size_t)c*HWHW] = v;
        s += v; ss += v*v;
    }
    float u  = s * (1.f/CC_);
    float var = ss * (1.f/CC_) - u*u;
    float rs = rsqrtf(var + 1e-5f);
    for (int c = 0; c < CC_; ++c) {
        float v = out[base + (size_t)c*HWHW];
        XLN[base + (size_t)c*HWHW] = (v-u)*rs*lw[c] + lb[c];
    }
}

// ---------------------------------------------------------------------------
// Fused MLP, hidden chunked by 96: out += gelu(XLN @ w1 + b1) @ w2 + b2
// Block: 384 thr, 32 tokens. thread = (c = tid%96, tq = tid/96 -> 8 tokens).
__global__ __launch_bounds__(384) void mlp2_kernel(const float* __restrict__ XLN,
                                                   const float* __restrict__ w1,
                                                   const float* __restrict__ b1,
                                                   const float* __restrict__ w2,
                                                   const float* __restrict__ b2,
                                                   float* __restrict__ out) {
    __shared__ float lx[32*97];          // [t][c] padded          12.4 KB
    __shared__ float lh[96*33];          // [j][t] padded          12.7 KB
    int blk = blockIdx.x;                // 784
    int tid = threadIdx.x;               // 384
    int p0  = blk * 32;
    int n   = p0 / HWHW;
    int hw0 = p0 % HWHW;
    const float* Xb = XLN + (size_t)n*CC_*HWHW + hw0;
    for (int idx = tid; idx < 32*CC_; idx += 384) {
        int c = idx / 32, t = idx % 32;
        lx[t*97 + c] = Xb[(size_t)c*HWHW + t];
    }
    __syncthreads();

    int c  = tid % CC_;                  // 0..95
    int tq = tid / CC_;                  // 0..3 -> tokens tq*8..+7
    float acc2[8] = {};

    for (int ch = 0; ch < 4; ++ch) {
        int j = ch*96 + c;
        float acc1[8] = {};
        const float* lxb = &lx[tq*8*97];
        for (int k = 0; k < CC_; ++k) {
            float wv = w1[(size_t)k*384 + j];
            #pragma unroll
            for (int i = 0; i < 8; ++i)
                acc1[i] = fmaf(lxb[i*97 + k], wv, acc1[i]);
        }
        __syncthreads();   // previous chunk's gemm2 reads of lh are done
        float bj = b1[j];
        #pragma unroll
        for (int i = 0; i < 8; ++i) {
            float h = acc1[i] + bj;
            h = 0.5f * h * (1.f + erff(h * 0.70710678118654752440f));
            lh[c*33 + tq*8 + i] = h;
        }
        __syncthreads();
        for (int k = 0; k < 96; ++k) {
            float wv = w2[(size_t)(ch*96 + k)*CC_ + c];
            #pragma unroll
            for (int i = 0; i < 8; ++i)
                acc2[i] = fmaf(lh[k*33 + tq*8 + i], wv, acc2[i]);
        }
    }
    float bv = b2[c];
    size_t obase = ((size_t)n*CC_ + c)*HWHW + hw0;
    #pragma unroll
    for (int i = 0; i < 8; ++i)
        out[obase + tq*8 + i] += acc2[i] + bv;
}

// ---------------------------------------------------------------------------
extern "C" void kernel_launch(void* const* d_in, const int* in_sizes, int n_in,
                              void* d_out, int out_size, void* d_ws, size_t ws_size,
                              hipStream_t stream) {
    const float* x    = (const float*)d_in[0];
    const float* ln1w = (const float*)d_in[1];
    const float* ln1b = (const float*)d_in[2];
    const float* wnn  = (const float*)d_in[3];
    const float* ln2w = (const float*)d_in[4];
    const float* ln2b = (const float*)d_in[5];
    const float* w1   = (const float*)d_in[6];
    const float* b1   = (const float*)d_in[7];
    const float* w2   = (const float*)d_in[8];
    const float* b2   = (const float*)d_in[9];
    float* out = (float*)d_out;
    float* ws  = (float*)d_ws;

    float* Wf = ws;                       // 21504
    float* Wt = Wf + WTOTAL;              // 21504
    float* X  = Wt + WTOTAL;              // NELEM
    float* Hu = X  + NELEM;               // NELEM
    float* R  = Hu + NELEM;               // NELEM (ratio, later XLN)
    float* S0 = R  + NELEM;               // NPIX
    float* S1 = S0 + NPIX;                // NPIX

    wnorm2_kernel<<<CC_, 256, 0, stream>>>(wnn, Wf, Wt);
    ln1_kernel<<<NPIX/256, 256, 0, stream>>>(x, ln1w, ln1b, X);
    fill_kernel<<<NELEM/256, 256, 0, stream>>>(Hu, NELEM, 1.f/CC_);
    fill_kernel<<<NPIX/256, 256, 0, stream>>>(S0, NPIX, 1.f);

    for (int it = 0; it < NITER; ++it) {
        float* Scur = (it & 1) ? S1 : S0;
        float* Snxt = (it & 1) ? S0 : S1;
        // R = X / (convT(Hu/S) + EPS); also zeroes Snxt
        conv3_kernel<0><<<448, 512, 0, stream>>>(Hu, Wt, X, Scur, Snxt, nullptr, R);
        // Hu = (Hu/S) * conv(R); Snxt += channel sums
        conv3_kernel<1><<<448, 512, 0, stream>>>(R, Wf, nullptr, Scur, Snxt, Hu, nullptr);
    }
    float* Sfin = S1;  // 25 iters: last writes S1

    resln2_kernel<<<NPIX/256, 256, 0, stream>>>(x, Hu, Sfin, ln2w, ln2b, out, R);
    mlp2_kernel<<<NPIX/32, 384, 0, stream>>>(R, w1, b1, w2, b2, out);
}